// Round 12
// baseline (132.454 us; speedup 1.0000x reference)
//
#include <hip/hip_runtime.h>

typedef __attribute__((ext_vector_type(8))) short short8;
typedef __attribute__((ext_vector_type(4))) float f32x4;
typedef __attribute__((ext_vector_type(16))) float f32x16;

__device__ __forceinline__ unsigned short f2b(float f) {
  union { float f; unsigned u; } x; x.f = f;
  unsigned r = (x.u + 0x7fffu + ((x.u >> 16) & 1u)) >> 16;
  return (unsigned short)r;
}
__device__ __forceinline__ float b2f(unsigned short b) {
  union { unsigned u; float f; } x; x.u = ((unsigned)b) << 16;
  return x.f;
}
__device__ __forceinline__ unsigned cvtpk(float lo, float hi) {
  unsigned r;
  asm("v_cvt_pk_bf16_f32 %0, %1, %2" : "=v"(r) : "v"(lo), "v"(hi));
  return r;
}
__device__ __forceinline__ void plswap(unsigned& a, unsigned& b) {
  asm volatile("v_permlane32_swap_b32 %0, %1" : "+v"(a), "+v"(b));
}

#define GLDS16(gp, lp)                                                                  \
  __builtin_amdgcn_global_load_lds((const __attribute__((address_space(1))) void*)(gp), \
                                   (__attribute__((address_space(3))) void*)(lp), 16, 0, 0)

// ---------------- weight conversion ----------------
__global__ void prep_w_kernel(const float* __restrict__ W_in, const float* __restrict__ W_attn,
                              const float* __restrict__ W_out, unsigned short* __restrict__ Wcat,
                              unsigned short* __restrict__ WoutB) {
  const int n1 = 2048 * 512, n2 = 512 * 512, n3 = 512 * 1024;
  for (int i = blockIdx.x * 256 + threadIdx.x; i < n1 + n2 + n3; i += gridDim.x * 256) {
    if (i < n1) Wcat[i] = f2b(W_in[i]);
    else if (i < n1 + n2) Wcat[i] = f2b(W_attn[i - n1]);
    else WoutB[i - n1 - n2] = f2b(W_out[i - n1 - n2]);
  }
}

// ---------------- x transpose: xT[b][t][c] = bf16(x[b][c][t]) ----------------
__global__ __launch_bounds__(256) void transpose_x_kernel(const float* __restrict__ x,
                                                          unsigned short* __restrict__ xT) {
  __shared__ float tile[32][33];
  const int bid = blockIdx.x;
  const int b = bid & 7;
  const int rem = bid >> 3;
  const int c0 = (rem >> 5) << 5;
  const int t0 = (rem & 31) << 5;
  const int tj = threadIdx.x & 31, ti = threadIdx.x >> 5;  // ti 0..7
#pragma unroll
  for (int r = 0; r < 32; r += 8)
    tile[ti + r][tj] = x[(((size_t)b << 9) + c0 + ti + r) * 1024 + t0 + tj];
  __syncthreads();
#pragma unroll
  for (int r = 0; r < 32; r += 8)
    xT[(((size_t)b << 10) + t0 + ti + r) * 512 + c0 + tj] = f2b(tile[tj][ti + r]);
}

// ---------------- shared GEMM core: 128x128 tile, BK=32, 4 waves, 2-buf, 1 barrier/step ----------------
// Slot swizzle (round-11 verified, conflicts 2.6M->0): LDS[row][slot s] holds global
// k-slot s ^ ((row>>1)&3); stage pre-swizzles the GLOBAL source col (dest linear),
// reads XOR the same. 2 buffers + single barrier: stage(t+1) is issued AFTER the
// barrier at top of t, into the buffer whose readers (iter t-1) finished before it.
__device__ __forceinline__ void gemm_stage(const unsigned short* Ag, const unsigned short* Bg,
                                           int lda, int ldb, int k0, unsigned short* lsA,
                                           unsigned short* lsB, int buf, int sr, int sk,
                                           int ldst) {
  const int bb = buf * 8192;  // bytes per buffer
  GLDS16(Ag + (size_t)sr * lda + k0 + sk, (char*)lsA + bb + ldst);
  GLDS16(Ag + (size_t)(sr + 64) * lda + k0 + sk, (char*)lsA + bb + 4096 + ldst);
  GLDS16(Bg + (size_t)sr * ldb + k0 + sk, (char*)lsB + bb + ldst);
  GLDS16(Bg + (size_t)(sr + 64) * ldb + k0 + sk, (char*)lsB + bb + 4096 + ldst);
}

__device__ __forceinline__ void gemm_bt_core(const unsigned short* __restrict__ Ag,
                                             const unsigned short* __restrict__ Bg, int lda,
                                             int ldb, int K, unsigned short* lsA,
                                             unsigned short* lsB, f32x4 acc[4][4]) {
  const int tid = threadIdx.x;
  const int lane = tid & 63;
  const int w = tid >> 6;
  const int wr = w >> 1, wc = w & 1;
  const int sr = tid >> 2;  // staging row 0..63 (rows sr and sr+64 share (sr>>1)&3)
  const int sk = (((tid & 3) ^ ((sr >> 1) & 3)) << 3);  // swizzled global k-slot (elems)
  const int ldst = (tid >> 6) << 10;  // wave-uniform LDS byte base

  const int nt = K >> 5;
  gemm_stage(Ag, Bg, lda, ldb, 0, lsA, lsB, 0, sr, sk, ldst);
  for (int t = 0; t < nt; ++t) {
    const int cur = t & 1;
    asm volatile("s_waitcnt vmcnt(0)" ::: "memory");  // own tile-t loads landed
    __builtin_amdgcn_s_barrier();  // all waves' tile-t loads visible; t-1 reads done
    if (t + 1 < nt)
      gemm_stage(Ag, Bg, lda, ldb, (t + 1) << 5, lsA, lsB, cur ^ 1, sr, sk, ldst);
    short8 af[4], bfr[4];
    const int bb = cur * 8192;
    const int ko = (lane >> 4) << 4;  // byte slot within 64B row
    const int ra = (wr << 6) + (lane & 15);
    const int rb = (wc << 6) + (lane & 15);
#pragma unroll
    for (int mi = 0; mi < 4; ++mi) {
      const int rowA = ra + (mi << 4);
      af[mi] = *(const short8*)((const char*)lsA + bb + (rowA << 6) +
                                (ko ^ (((rowA >> 1) & 3) << 4)));
    }
#pragma unroll
    for (int ni = 0; ni < 4; ++ni) {
      const int rowB = rb + (ni << 4);
      bfr[ni] = *(const short8*)((const char*)lsB + bb + (rowB << 6) +
                                 (ko ^ (((rowB >> 1) & 3) << 4)));
    }
#pragma unroll
    for (int mi = 0; mi < 4; ++mi)
#pragma unroll
      for (int ni = 0; ni < 4; ++ni)
        acc[mi][ni] =
            __builtin_amdgcn_mfma_f32_16x16x32_bf16(af[mi], bfr[ni], acc[mi][ni], 0, 0, 0);
  }
}

// ---------------- GEMM A: [W_in;W_attn](2560x512) @ x[b](512x1024) ----------------
// u is written as [b][t][e] (t-major) so the 4-consecutive-row C fragment becomes one
// ushort4 store; attn reads u the same way (ushort4 over e).
__global__ __launch_bounds__(256) void gemm_a_kernel(
    const unsigned short* __restrict__ Wcat, const unsigned short* __restrict__ xT,
    const float* __restrict__ b_in, const float* __restrict__ b_attn,
    const float* __restrict__ w_q, const float* __restrict__ b_q, const float* __restrict__ w_k,
    const float* __restrict__ b_k, unsigned short* __restrict__ u, unsigned short* __restrict__ v,
    unsigned short* __restrict__ qT, unsigned short* __restrict__ kT) {
  __shared__ __align__(16) unsigned short lsA[8192];  // 2 x 8KB
  __shared__ __align__(16) unsigned short lsB[8192];
  // XCD swizzle: 1280 = 8 XCDs x 160; each XCD owns one batch b (W+x ~3.6MB fits L2)
  const int bid = ((blockIdx.x & 7) * 160) + (blockIdx.x >> 3);
  const int b = bid / 160;
  const int rem = bid % 160;
  const int m0 = (rem >> 3) << 7;
  const int n0 = (rem & 7) << 7;
  f32x4 acc[4][4];
  const f32x4 z4 = {0.f, 0.f, 0.f, 0.f};
#pragma unroll
  for (int mi = 0; mi < 4; ++mi)
#pragma unroll
    for (int ni = 0; ni < 4; ++ni) acc[mi][ni] = z4;

  const unsigned short* Ag = Wcat + (size_t)m0 * 512;
  const unsigned short* Bg = xT + ((size_t)b << 19) + ((size_t)n0 << 9);
  gemm_bt_core(Ag, Bg, 512, 512, 512, lsA, lsB, acc);

  const int lane = threadIdx.x & 63;
  const int w = threadIdx.x >> 6;
  const int wr = w >> 1, wc = w & 1;
#pragma unroll
  for (int mi = 0; mi < 4; ++mi) {
    const int row0 = m0 + (wr << 6) + (mi << 4) + ((lane >> 4) << 2);
#pragma unroll
    for (int ni = 0; ni < 4; ++ni) {
      const int col = n0 + (wc << 6) + (ni << 4) + (lane & 15);
      if (row0 < 1024) {
        ushort4 uv;
        unsigned short* up = (unsigned short*)&uv;
#pragma unroll
        for (int i = 0; i < 4; ++i) {
          const int row = row0 + i;
          const float s = acc[mi][ni][i] + b_in[row];
          up[i] = f2b(s / (1.f + __expf(-s)));  // silu
        }
        *(ushort4*)(u + ((((size_t)b << 10) + col) << 10) + row0) = uv;  // u[b][t][e]
      } else if (row0 < 2048) {
#pragma unroll
        for (int i = 0; i < 4; ++i) {
          const int row = row0 + i;
          const float s = acc[mi][ni][i] + b_in[row];
          const float r = s / (1.f + __expf(-s));  // silu
          v[((((size_t)b << 10) + (row - 1024)) << 10) + col] = f2b(r);
        }
      } else {
        const int c0 = row0 - 2048;
        ushort4 qv, kv;
        unsigned short* qp = (unsigned short*)&qv;
        unsigned short* kp = (unsigned short*)&kv;
#pragma unroll
        for (int i = 0; i < 4; ++i) {
          const int c = c0 + i;
          const float z = acc[mi][ni][i] + b_attn[c];
          qp[i] = f2b(z * w_q[c] + b_q[c]);
          kp[i] = f2b(z * w_k[c] + b_k[c]);
        }
        const int h = c0 >> 6, d = c0 & 63;
        const size_t base = ((((size_t)b * 8 + h) << 10) + col) * 64 + d;
        *(ushort4*)(qT + base) = qv;
        *(ushort4*)(kT + base) = kv;
      }
    }
  }
}

// ---------------- flash attention v5: QBLK=128, 4 waves, 3-buf K/V, 1 barrier/kt ----------------
__global__ __launch_bounds__(256, 2) void attn_kernel(const unsigned short* __restrict__ qT,
                                                      const unsigned short* __restrict__ kT,
                                                      const unsigned short* __restrict__ v,
                                                      const unsigned short* __restrict__ u,
                                                      unsigned short* __restrict__ uoT) {
  __shared__ __align__(16) unsigned short Kls[3 * 4096];  // 3 x [64 k][64 d] swizzled
  __shared__ __align__(16) unsigned short Vls[3 * 8192];  // 3 x [128 e][64 t] swizzled
  const float SCALE2 = 0.20037430567f;  // (log(1024)/log(512)/sqrt(64)) * log2(e)
  const int bx = blockIdx.x;
  const int xcd = bx & 7, idx = bx >> 3;  // idx 0..63
  const int bh = (xcd << 3) + (idx & 7);
  const int qb = idx >> 3;  // 0..7
  const int b = bh >> 3, h = bh & 7;
  const int tid = threadIdx.x;
  const int lane = tid & 63;
  const int w = tid >> 6;  // qw 0..3
  const int l5 = lane >> 5;
  const int l31 = lane & 31;
  const int q0 = qb << 7;

  const unsigned short* qh = qT + ((size_t)bh << 16);
  const unsigned short* kh = kT + ((size_t)bh << 16);
  const unsigned short* vh = v + ((((size_t)b << 10) + (h << 7)) << 10);

  short8 qf[4];
#pragma unroll
  for (int ds = 0; ds < 4; ++ds)
    qf[ds] = *(const short8*)(qh + (size_t)(q0 + (w << 5) + l31) * 64 + (ds << 4) + (l5 << 3));

  f32x16 o[4];
#pragma unroll
  for (int eb = 0; eb < 4; ++eb)
#pragma unroll
    for (int i = 0; i < 16; ++i) o[eb][i] = 0.f;
  float lacc = 0.f;

  // staging: 256 threads; each covers row tid>>3 (0..31), 16B slot tid&7; src pre-swizzled
  const int srow = tid >> 3;                         // 0..31
  const int scol = (((tid & 7) ^ (srow & 7)) << 3);  // element offset

#define ATTN_STAGE(buf, kt)                                                            \
  {                                                                                    \
    const int t2 = (kt) << 6;                                                          \
    char* kbase = (char*)Kls + (buf)*8192;                                             \
    char* vbase = (char*)Vls + (buf)*16384;                                            \
    GLDS16(kh + (size_t)(t2 + srow) * 64 + scol, kbase + (w << 10));                   \
    GLDS16(kh + (size_t)(t2 + 32 + srow) * 64 + scol, kbase + 4096 + (w << 10));       \
    GLDS16(vh + ((size_t)srow << 10) + t2 + scol, vbase + (w << 10));                  \
    GLDS16(vh + ((size_t)(32 + srow) << 10) + t2 + scol, vbase + 4096 + (w << 10));    \
    GLDS16(vh + ((size_t)(64 + srow) << 10) + t2 + scol, vbase + 8192 + (w << 10));    \
    GLDS16(vh + ((size_t)(96 + srow) << 10) + t2 + scol, vbase + 12288 + (w << 10));   \
  }

  int c0b = 0, c1b = 1, c2b = 2;
  ATTN_STAGE(0, 0);
  ATTN_STAGE(1, 1);
  union U8 { short8 s8; unsigned u4[4]; };
  for (int kt = 0; kt < 16; ++kt) {
    if (kt < 15) {
      asm volatile("s_waitcnt vmcnt(6)" ::: "memory");  // tile kt landed (kt+1 in flight)
    } else {
      asm volatile("s_waitcnt vmcnt(0)" ::: "memory");
    }
    __builtin_amdgcn_s_barrier();  // all tile-kt loads visible; kt-1 reads done
    if (kt < 14) ATTN_STAGE(c2b, kt + 2);

    const char* kb = (const char*)Kls + c0b * 8192;
    const char* vb = (const char*)Vls + c0b * 16384;
    U8 pf[4];

    // ---- k-half 0: S^T = mfma(K,Q), exp2, pack ----
    {
      f32x16 s;
#pragma unroll
      for (int i = 0; i < 16; ++i) s[i] = 0.f;
      const int kr = l31;
      __builtin_amdgcn_s_setprio(1);
#pragma unroll
      for (int ds = 0; ds < 4; ++ds) {
        short8 kf = *(const short8*)(kb + (kr << 7) +
                                     (((ds << 5) + (l5 << 4)) ^ ((kr & 7) << 4)));
        s = __builtin_amdgcn_mfma_f32_32x32x16_bf16(kf, qf[ds], s, 0, 0, 0);
      }
      __builtin_amdgcn_s_setprio(0);
      float p[16];
#pragma unroll
      for (int i = 0; i < 16; ++i) {
        p[i] = exp2f(s[i] * SCALE2);
        lacc += p[i];
      }
      unsigned W00 = cvtpk(p[0], p[1]), W01 = cvtpk(p[2], p[3]);
      unsigned W10 = cvtpk(p[4], p[5]), W11 = cvtpk(p[6], p[7]);
      unsigned W20 = cvtpk(p[8], p[9]), W21 = cvtpk(p[10], p[11]);
      unsigned W30 = cvtpk(p[12], p[13]), W31 = cvtpk(p[14], p[15]);
      unsigned a = W10, bq = W00; plswap(a, bq);
      pf[0].u4[0] = bq; pf[0].u4[2] = a;
      unsigned c = W11, d = W01; plswap(c, d);
      pf[0].u4[1] = d; pf[0].u4[3] = c;
      unsigned e = W30, f = W20; plswap(e, f);
      pf[1].u4[0] = f; pf[1].u4[2] = e;
      unsigned g = W31, hh = W21; plswap(g, hh);
      pf[1].u4[1] = hh; pf[1].u4[3] = g;
    }
    // ---- k-half 1 ----
    {
      f32x16 s;
#pragma unroll
      for (int i = 0; i < 16; ++i) s[i] = 0.f;
      const int kr = 32 + l31;
      __builtin_amdgcn_s_setprio(1);
#pragma unroll
      for (int ds = 0; ds < 4; ++ds) {
        short8 kf = *(const short8*)(kb + (kr << 7) +
                                     (((ds << 5) + (l5 << 4)) ^ ((kr & 7) << 4)));
        s = __builtin_amdgcn_mfma_f32_32x32x16_bf16(kf, qf[ds], s, 0, 0, 0);
      }
      __builtin_amdgcn_s_setprio(0);
      float p[16];
#pragma unroll
      for (int i = 0; i < 16; ++i) {
        p[i] = exp2f(s[i] * SCALE2);
        lacc += p[i];
      }
      unsigned W00 = cvtpk(p[0], p[1]), W01 = cvtpk(p[2], p[3]);
      unsigned W10 = cvtpk(p[4], p[5]), W11 = cvtpk(p[6], p[7]);
      unsigned W20 = cvtpk(p[8], p[9]), W21 = cvtpk(p[10], p[11]);
      unsigned W30 = cvtpk(p[12], p[13]), W31 = cvtpk(p[14], p[15]);
      unsigned a = W10, bq = W00; plswap(a, bq);
      pf[2].u4[0] = bq; pf[2].u4[2] = a;
      unsigned c = W11, d = W01; plswap(c, d);
      pf[2].u4[1] = d; pf[2].u4[3] = c;
      unsigned e = W30, f = W20; plswap(e, f);
      pf[3].u4[0] = f; pf[3].u4[2] = e;
      unsigned g = W31, hh = W21; plswap(g, hh);
      pf[3].u4[1] = hh; pf[3].u4[3] = g;
    }

    // ---- O += V^T x P over ALL 128 e ----
    __builtin_amdgcn_s_setprio(1);
#pragma unroll
    for (int eb = 0; eb < 4; ++eb) {
      const int vrow = (eb << 5) + l31;
#pragma unroll
      for (int ks = 0; ks < 4; ++ks) {
        short8 vf = *(const short8*)(vb + (vrow << 7) +
                                     (((ks << 5) + (l5 << 4)) ^ ((vrow & 7) << 4)));
        o[eb] = __builtin_amdgcn_mfma_f32_32x32x16_bf16(vf, pf[ks].s8, o[eb], 0, 0, 0);
      }
    }
    __builtin_amdgcn_s_setprio(0);
    const int tmp = c0b; c0b = c1b; c1b = c2b; c2b = tmp;
  }
#undef ATTN_STAGE

  // ---- finalize: full row sum = this l5-half + partner half ----
  lacc += __shfl_xor(lacc, 32, 64);
  const float rl = 1.f / lacc;
  const int t = q0 + (w << 5) + l31;

  // ---- epilogue: uoT[b][t][h*128+e] = bf16(u * o / l); u is [b][t][e] ----
#pragma unroll
  for (int eb = 0; eb < 4; ++eb) {
#pragma unroll
    for (int g = 0; g < 4; ++g) {
      const int e4 = (eb << 5) + (g << 3) + (l5 << 2);
      const int eg = (h << 7) + e4;
      const ushort4 uu = *(const ushort4*)(u + ((((size_t)b << 10) + t) << 10) + eg);
      const unsigned short* ua = (const unsigned short*)&uu;
      ushort4 outv;
      unsigned short* op = (unsigned short*)&outv;
#pragma unroll
      for (int j = 0; j < 4; ++j) {
        const int i = (g << 2) + j;
        const float oo = o[eb][i] * rl;
        op[j] = f2b(oo * b2f(ua[j]));
      }
      *(ushort4*)(uoT + ((((size_t)b << 10) + t) << 10) + eg) = outv;
    }
  }
}

// ---------------- GEMM C: out^T = uoT(1024x1024) @ W_out^T, +bias+residual -> y(bf16) ----------------
__global__ __launch_bounds__(256) void gemm_c_kernel(const unsigned short* __restrict__ uoT,
                                                     const unsigned short* __restrict__ WoutB,
                                                     const float* __restrict__ x,
                                                     const float* __restrict__ b_out,
                                                     unsigned short* __restrict__ y) {
  __shared__ __align__(16) unsigned short lsA[8192];
  __shared__ __align__(16) unsigned short lsB[8192];
  // XCD swizzle: 256 = 8 x 32
  const int bid = ((blockIdx.x & 7) * 32) + (blockIdx.x >> 3);
  const int b = bid >> 5;
  const int rem = bid & 31;
  const int m0 = (rem >> 2) << 7;  // t tile
  const int n0 = (rem & 3) << 7;   // c tile
  f32x4 acc[4][4];
  const f32x4 z4 = {0.f, 0.f, 0.f, 0.f};
#pragma unroll
  for (int mi = 0; mi < 4; ++mi)
#pragma unroll
    for (int ni = 0; ni < 4; ++ni) acc[mi][ni] = z4;

  const unsigned short* Ag = uoT + ((size_t)b << 20) + ((size_t)m0 << 10);
  const unsigned short* Bg = WoutB + ((size_t)n0 << 10);
  gemm_bt_core(Ag, Bg, 1024, 1024, 1024, lsA, lsB, acc);

  const int lane = threadIdx.x & 63;
  const int w = threadIdx.x >> 6;
  const int wr = w >> 1, wc = w & 1;
#pragma unroll
  for (int mi = 0; mi < 4; ++mi) {
    const int t4 = m0 + (wr << 6) + (mi << 4) + ((lane >> 4) << 2);
#pragma unroll
    for (int ni = 0; ni < 4; ++ni) {
      const int c = n0 + (wc << 6) + (ni << 4) + (lane & 15);
      const size_t base = ((((size_t)b << 9) + c) << 10) + t4;
      const f32x4 xv = *(const f32x4*)(x + base);
      const float bo = b_out[c];
      ushort4 ov;
      unsigned short* op = (unsigned short*)&ov;
#pragma unroll
      for (int i = 0; i < 4; ++i) op[i] = f2b(acc[mi][ni][i] + bo + xv[i]);
      *(ushort4*)(y + base) = ov;
    }
  }
}

// ---------------- RMSNorm over C per (b,t): y bf16 in, f32 out ----------------
__global__ __launch_bounds__(256) void rms_kernel(const unsigned short* __restrict__ y,
                                                  const float* __restrict__ gamma,
                                                  float* __restrict__ out) {
  __shared__ float part[8][32];
  __shared__ float rmsv[32];
  const int bid = blockIdx.x;
  const int b = bid >> 5;
  const int t0 = (bid & 31) << 5;  // 32 t per block
  const int tid = threadIdx.x;
  const int tt = tid & 31, cg = tid >> 5;  // cg 0..7, 64 c each
  const int t = t0 + tt;
  float vals[64];
  float ss = 0.f;
#pragma unroll
  for (int ci = 0; ci < 64; ++ci) {
    const int c = (cg << 6) + ci;
    const float vv = b2f(y[((((size_t)b << 9) + c) << 10) + t]);
    vals[ci] = vv;
    ss += vv * vv;
  }
  part[cg][tt] = ss;
  __syncthreads();
  if (tid < 32) {
    float tot = 0.f;
#pragma unroll
    for (int g = 0; g < 8; ++g) tot += part[g][tid];
    rmsv[tid] = rsqrtf(tot / 512.f + 1e-5f);
  }
  __syncthreads();
  const float rm = rmsv[tt];
#pragma unroll
  for (int ci = 0; ci < 64; ++ci) {
    const int c = (cg << 6) + ci;
    out[((((size_t)b << 9) + c) << 10) + t] = vals[ci] * rm * gamma[c];
  }
}

extern "C" void kernel_launch(void* const* d_in, const int* in_sizes, int n_in, void* d_out,
                              int out_size, void* d_ws, size_t ws_size, hipStream_t stream) {
  const float* x = (const float*)d_in[0];
  const float* W_in = (const float*)d_in[1];
  const float* b_in = (const float*)d_in[2];
  const float* W_attn = (const float*)d_in[3];
  const float* b_attn = (const float*)d_in[4];
  const float* w_q = (const float*)d_in[5];
  const float* b_q = (const float*)d_in[6];
  const float* w_k = (const float*)d_in[7];
  const float* b_k = (const float*)d_in[8];
  const float* W_out = (const float*)d_in[9];
  const float* b_out = (const float*)d_in[10];
  const float* gamma = (const float*)d_in[11];
  float* out = (float*)d_out;

  char* ws = (char*)d_ws;
  size_t off = 0;
  auto alloc = [&](size_t bytes) {
    char* p = ws + off;
    off += (bytes + 255) & ~(size_t)255;
    return p;
  };
  unsigned short* Wcat = (unsigned short*)alloc((size_t)2560 * 512 * 2);
  unsigned short* WoutB = (unsigned short*)alloc((size_t)512 * 1024 * 2);
  unsigned short* xT = (unsigned short*)alloc((size_t)8 * 1024 * 512 * 2);
  unsigned short* u = (unsigned short*)alloc((size_t)8 * 1024 * 1024 * 2);
  unsigned short* v = (unsigned short*)alloc((size_t)8 * 1024 * 1024 * 2);
  unsigned short* qT = (unsigned short*)alloc((size_t)8 * 8 * 1024 * 64 * 2);
  unsigned short* kT = (unsigned short*)alloc((size_t)8 * 8 * 1024 * 64 * 2);
  unsigned short* uoT = (unsigned short*)alloc((size_t)8 * 1024 * 1024 * 2);
  unsigned short* y = (unsigned short*)alloc((size_t)8 * 512 * 1024 * 2);
  if (off > ws_size) return;  // fail visibly (poisoned output)

  prep_w_kernel<<<896, 256, 0, stream>>>(W_in, W_attn, W_out, Wcat, WoutB);
  transpose_x_kernel<<<4096, 256, 0, stream>>>(x, xT);
  gemm_a_kernel<<<1280, 256, 0, stream>>>(Wcat, xT, b_in, b_attn, w_q, b_q, w_k, b_k, u, v, qT,
                                          kT);
  attn_kernel<<<512, 256, 0, stream>>>(qT, kT, v, u, uoT);
  gemm_c_kernel<<<256, 256, 0, stream>>>(uoT, WoutB, x, b_out, y);
  rms_kernel<<<256, 256, 0, stream>>>(y, gamma, out);
}

// Round 13
// 123.996 us; speedup vs baseline: 1.0682x; 1.0682x over previous
//
#include <hip/hip_runtime.h>

typedef __attribute__((ext_vector_type(8))) short short8;
typedef __attribute__((ext_vector_type(4))) float f32x4;
typedef __attribute__((ext_vector_type(16))) float f32x16;

__device__ __forceinline__ unsigned short f2b(float f) {
  union { float f; unsigned u; } x; x.f = f;
  unsigned r = (x.u + 0x7fffu + ((x.u >> 16) & 1u)) >> 16;
  return (unsigned short)r;
}
__device__ __forceinline__ float b2f(unsigned short b) {
  union { unsigned u; float f; } x; x.u = ((unsigned)b) << 16;
  return x.f;
}
__device__ __forceinline__ unsigned cvtpk(float lo, float hi) {
  unsigned r;
  asm("v_cvt_pk_bf16_f32 %0, %1, %2" : "=v"(r) : "v"(lo), "v"(hi));
  return r;
}
__device__ __forceinline__ void plswap(unsigned& a, unsigned& b) {
  asm volatile("v_permlane32_swap_b32 %0, %1" : "+v"(a), "+v"(b));
}

#define GLDS16(gp, lp)                                                                  \
  __builtin_amdgcn_global_load_lds((const __attribute__((address_space(1))) void*)(gp), \
                                   (__attribute__((address_space(3))) void*)(lp), 16, 0, 0)

// ---------------- weight conversion ----------------
__global__ void prep_w_kernel(const float* __restrict__ W_in, const float* __restrict__ W_attn,
                              const float* __restrict__ W_out, unsigned short* __restrict__ Wcat,
                              unsigned short* __restrict__ WoutB) {
  const int n1 = 2048 * 512, n2 = 512 * 512, n3 = 512 * 1024;
  for (int i = blockIdx.x * 256 + threadIdx.x; i < n1 + n2 + n3; i += gridDim.x * 256) {
    if (i < n1) Wcat[i] = f2b(W_in[i]);
    else if (i < n1 + n2) Wcat[i] = f2b(W_attn[i - n1]);
    else WoutB[i - n1 - n2] = f2b(W_out[i - n1 - n2]);
  }
}

// ---------------- x transpose: xT[b][t][c] = bf16(x[b][c][t]) ----------------
__global__ __launch_bounds__(256) void transpose_x_kernel(const float* __restrict__ x,
                                                          unsigned short* __restrict__ xT) {
  __shared__ float tile[32][33];
  const int bid = blockIdx.x;
  const int b = bid & 7;
  const int rem = bid >> 3;
  const int c0 = (rem >> 5) << 5;
  const int t0 = (rem & 31) << 5;
  const int tj = threadIdx.x & 31, ti = threadIdx.x >> 5;  // ti 0..7
#pragma unroll
  for (int r = 0; r < 32; r += 8)
    tile[ti + r][tj] = x[(((size_t)b << 9) + c0 + ti + r) * 1024 + t0 + tj];
  __syncthreads();
#pragma unroll
  for (int r = 0; r < 32; r += 8)
    xT[(((size_t)b << 10) + t0 + ti + r) * 512 + c0 + tj] = f2b(tile[tj][ti + r]);
}

// ---------------- shared GEMM core: 128x128 tile, BK=32, 4 waves, 3-buf, 1 barrier/step ----------------
// LDS rows are 64B (32 bf16). Slot swizzle: LDS[row][slot s] holds global k-slot
// s ^ ((row>>1)&3). Stage pre-swizzles the GLOBAL source column (dest stays linear,
// as global_load_lds requires); reads XOR the same value. 8-lane phase groups of
// ds_read_b128 then cover all 8 (half,slot) bank-quads -> conflict-free.
__device__ __forceinline__ void gemm_stage(const unsigned short* Ag, const unsigned short* Bg,
                                           int lda, int ldb, int k0, unsigned short* lsA,
                                           unsigned short* lsB, int buf, int sr, int sk,
                                           int ldst) {
  const int bb = buf * 8192;  // bytes per buffer
  GLDS16(Ag + (size_t)sr * lda + k0 + sk, (char*)lsA + bb + ldst);
  GLDS16(Ag + (size_t)(sr + 64) * lda + k0 + sk, (char*)lsA + bb + 4096 + ldst);
  GLDS16(Bg + (size_t)sr * ldb + k0 + sk, (char*)lsB + bb + ldst);
  GLDS16(Bg + (size_t)(sr + 64) * ldb + k0 + sk, (char*)lsB + bb + 4096 + ldst);
}

__device__ __forceinline__ void gemm_bt_core(const unsigned short* __restrict__ Ag,
                                             const unsigned short* __restrict__ Bg, int lda,
                                             int ldb, int K, unsigned short* lsA,
                                             unsigned short* lsB, f32x4 acc[4][4]) {
  const int tid = threadIdx.x;
  const int lane = tid & 63;
  const int w = tid >> 6;
  const int wr = w >> 1, wc = w & 1;
  const int sr = tid >> 2;  // staging row 0..63 (row sr and sr+64 share (sr>>1)&3 mod 4)
  const int sk = (((tid & 3) ^ ((sr >> 1) & 3)) << 3);  // swizzled global k-slot (elems)
  const int ldst = (tid >> 6) << 10;  // wave-uniform LDS byte base

  const int nt = K >> 5;
  int c0b = 0, c1b = 1, c2b = 2;
  gemm_stage(Ag, Bg, lda, ldb, 0, lsA, lsB, 0, sr, sk, ldst);
  gemm_stage(Ag, Bg, lda, ldb, 32, lsA, lsB, 1, sr, sk, ldst);
  for (int t = 0; t < nt; ++t) {
    if (t + 1 < nt) {
      asm volatile("s_waitcnt vmcnt(4)" ::: "memory");  // tile t landed (leaves t+1 in flight)
    } else {
      asm volatile("s_waitcnt vmcnt(0)" ::: "memory");
    }
    __builtin_amdgcn_s_barrier();  // all threads' tile-t loads visible; t-1 reads done
    if (t + 2 < nt)
      gemm_stage(Ag, Bg, lda, ldb, (t + 2) << 5, lsA, lsB, c2b, sr, sk, ldst);
    short8 af[4], bfr[4];
    const int bb = c0b * 8192;
    const int ko = (lane >> 4) << 4;  // byte slot within 64B row
    const int ra = (wr << 6) + (lane & 15);
    const int rb = (wc << 6) + (lane & 15);
#pragma unroll
    for (int mi = 0; mi < 4; ++mi) {
      const int rowA = ra + (mi << 4);
      af[mi] = *(const short8*)((const char*)lsA + bb + (rowA << 6) +
                                (ko ^ (((rowA >> 1) & 3) << 4)));
    }
#pragma unroll
    for (int ni = 0; ni < 4; ++ni) {
      const int rowB = rb + (ni << 4);
      bfr[ni] = *(const short8*)((const char*)lsB + bb + (rowB << 6) +
                                 (ko ^ (((rowB >> 1) & 3) << 4)));
    }
#pragma unroll
    for (int mi = 0; mi < 4; ++mi)
#pragma unroll
      for (int ni = 0; ni < 4; ++ni)
        acc[mi][ni] =
            __builtin_amdgcn_mfma_f32_16x16x32_bf16(af[mi], bfr[ni], acc[mi][ni], 0, 0, 0);
    const int tmp = c0b; c0b = c1b; c1b = c2b; c2b = tmp;
  }
}

// ---------------- GEMM A: [W_in;W_attn](2560x512) @ x[b](512x1024) ----------------
__global__ __launch_bounds__(256) void gemm_a_kernel(
    const unsigned short* __restrict__ Wcat, const unsigned short* __restrict__ xT,
    const float* __restrict__ b_in, const float* __restrict__ b_attn,
    const float* __restrict__ w_q, const float* __restrict__ b_q, const float* __restrict__ w_k,
    const float* __restrict__ b_k, unsigned short* __restrict__ u, unsigned short* __restrict__ v,
    unsigned short* __restrict__ qT, unsigned short* __restrict__ kT) {
  __shared__ __align__(16) unsigned short lsA[12288];  // 3 x 8KB
  __shared__ __align__(16) unsigned short lsB[12288];
  // XCD swizzle: 1280 = 8 XCDs x 160; each XCD owns one batch b (W+x ~3.6MB fits L2)
  const int bid = ((blockIdx.x & 7) * 160) + (blockIdx.x >> 3);
  const int b = bid / 160;
  const int rem = bid % 160;
  const int m0 = (rem >> 3) << 7;
  const int n0 = (rem & 7) << 7;
  f32x4 acc[4][4];
  const f32x4 z4 = {0.f, 0.f, 0.f, 0.f};
#pragma unroll
  for (int mi = 0; mi < 4; ++mi)
#pragma unroll
    for (int ni = 0; ni < 4; ++ni) acc[mi][ni] = z4;

  const unsigned short* Ag = Wcat + (size_t)m0 * 512;
  const unsigned short* Bg = xT + ((size_t)b << 19) + ((size_t)n0 << 9);
  gemm_bt_core(Ag, Bg, 512, 512, 512, lsA, lsB, acc);

  const int lane = threadIdx.x & 63;
  const int w = threadIdx.x >> 6;
  const int wr = w >> 1, wc = w & 1;
#pragma unroll
  for (int mi = 0; mi < 4; ++mi) {
    const int row0 = m0 + (wr << 6) + (mi << 4) + ((lane >> 4) << 2);
#pragma unroll
    for (int ni = 0; ni < 4; ++ni) {
      const int col = n0 + (wc << 6) + (ni << 4) + (lane & 15);
      if (row0 < 2048) {
#pragma unroll
        for (int i = 0; i < 4; ++i) {
          const int row = row0 + i;
          const float s = acc[mi][ni][i] + b_in[row];
          const float r = s / (1.f + __expf(-s));  // silu
          if (row < 1024)
            u[((((size_t)b << 10) + row) << 10) + col] = f2b(r);
          else
            v[((((size_t)b << 10) + (row - 1024)) << 10) + col] = f2b(r);
        }
      } else {
        const int c0 = row0 - 2048;
        ushort4 qv, kv;
        unsigned short* qp = (unsigned short*)&qv;
        unsigned short* kp = (unsigned short*)&kv;
#pragma unroll
        for (int i = 0; i < 4; ++i) {
          const int c = c0 + i;
          const float z = acc[mi][ni][i] + b_attn[c];
          qp[i] = f2b(z * w_q[c] + b_q[c]);
          kp[i] = f2b(z * w_k[c] + b_k[c]);
        }
        const int h = c0 >> 6, d = c0 & 63;
        const size_t base = ((((size_t)b * 8 + h) << 10) + col) * 64 + d;
        *(ushort4*)(qT + base) = qv;
        *(ushort4*)(kT + base) = kv;
      }
    }
  }
}

// ---------------- flash attention v5: QBLK=128, 4 waves, 3-buf K/V, 1 barrier/kt ----------------
__global__ __launch_bounds__(256, 2) void attn_kernel(const unsigned short* __restrict__ qT,
                                                      const unsigned short* __restrict__ kT,
                                                      const unsigned short* __restrict__ v,
                                                      const unsigned short* __restrict__ u,
                                                      unsigned short* __restrict__ uoT) {
  __shared__ __align__(16) unsigned short Kls[3 * 4096];  // 3 x [64 k][64 d] swizzled
  __shared__ __align__(16) unsigned short Vls[3 * 8192];  // 3 x [128 e][64 t] swizzled
  const float SCALE2 = 0.20037430567f;  // (log(1024)/log(512)/sqrt(64)) * log2(e)
  const int bx = blockIdx.x;
  const int xcd = bx & 7, idx = bx >> 3;  // idx 0..63
  const int bh = (xcd << 3) + (idx & 7);
  const int qb = idx >> 3;  // 0..7
  const int b = bh >> 3, h = bh & 7;
  const int tid = threadIdx.x;
  const int lane = tid & 63;
  const int w = tid >> 6;  // qw 0..3
  const int l5 = lane >> 5;
  const int l31 = lane & 31;
  const int q0 = qb << 7;

  const unsigned short* qh = qT + ((size_t)bh << 16);
  const unsigned short* kh = kT + ((size_t)bh << 16);
  const unsigned short* vh = v + ((((size_t)b << 10) + (h << 7)) << 10);

  short8 qf[4];
#pragma unroll
  for (int ds = 0; ds < 4; ++ds)
    qf[ds] = *(const short8*)(qh + (size_t)(q0 + (w << 5) + l31) * 64 + (ds << 4) + (l5 << 3));

  f32x16 o[4];
#pragma unroll
  for (int eb = 0; eb < 4; ++eb)
#pragma unroll
    for (int i = 0; i < 16; ++i) o[eb][i] = 0.f;
  float lacc = 0.f;

  // staging: 256 threads; each covers row tid>>3 (0..31), 16B slot tid&7; src pre-swizzled
  const int srow = tid >> 3;                         // 0..31
  const int scol = (((tid & 7) ^ (srow & 7)) << 3);  // element offset

#define ATTN_STAGE(buf, kt)                                                            \
  {                                                                                    \
    const int t2 = (kt) << 6;                                                          \
    char* kbase = (char*)Kls + (buf)*8192;                                             \
    char* vbase = (char*)Vls + (buf)*16384;                                            \
    GLDS16(kh + (size_t)(t2 + srow) * 64 + scol, kbase + (w << 10));                   \
    GLDS16(kh + (size_t)(t2 + 32 + srow) * 64 + scol, kbase + 4096 + (w << 10));       \
    GLDS16(vh + ((size_t)srow << 10) + t2 + scol, vbase + (w << 10));                  \
    GLDS16(vh + ((size_t)(32 + srow) << 10) + t2 + scol, vbase + 4096 + (w << 10));    \
    GLDS16(vh + ((size_t)(64 + srow) << 10) + t2 + scol, vbase + 8192 + (w << 10));    \
    GLDS16(vh + ((size_t)(96 + srow) << 10) + t2 + scol, vbase + 12288 + (w << 10));   \
  }

  int c0b = 0, c1b = 1, c2b = 2;
  ATTN_STAGE(0, 0);
  ATTN_STAGE(1, 1);
  union U8 { short8 s8; unsigned u4[4]; };
  for (int kt = 0; kt < 16; ++kt) {
    if (kt < 15) {
      asm volatile("s_waitcnt vmcnt(6)" ::: "memory");  // tile kt landed (kt+1 in flight)
    } else {
      asm volatile("s_waitcnt vmcnt(0)" ::: "memory");
    }
    __builtin_amdgcn_s_barrier();  // all tile-kt loads visible; kt-1 reads done
    if (kt < 14) ATTN_STAGE(c2b, kt + 2);

    const char* kb = (const char*)Kls + c0b * 8192;
    const char* vb = (const char*)Vls + c0b * 16384;
    U8 pf[4];

    // ---- k-half 0: S^T = mfma(K,Q), exp2, pack ----
    {
      f32x16 s;
#pragma unroll
      for (int i = 0; i < 16; ++i) s[i] = 0.f;
      const int kr = l31;
      __builtin_amdgcn_s_setprio(1);
#pragma unroll
      for (int ds = 0; ds < 4; ++ds) {
        short8 kf = *(const short8*)(kb + (kr << 7) +
                                     (((ds << 5) + (l5 << 4)) ^ ((kr & 7) << 4)));
        s = __builtin_amdgcn_mfma_f32_32x32x16_bf16(kf, qf[ds], s, 0, 0, 0);
      }
      __builtin_amdgcn_s_setprio(0);
      float p[16];
#pragma unroll
      for (int i = 0; i < 16; ++i) {
        p[i] = exp2f(s[i] * SCALE2);
        lacc += p[i];
      }
      unsigned W00 = cvtpk(p[0], p[1]), W01 = cvtpk(p[2], p[3]);
      unsigned W10 = cvtpk(p[4], p[5]), W11 = cvtpk(p[6], p[7]);
      unsigned W20 = cvtpk(p[8], p[9]), W21 = cvtpk(p[10], p[11]);
      unsigned W30 = cvtpk(p[12], p[13]), W31 = cvtpk(p[14], p[15]);
      unsigned a = W10, bq = W00; plswap(a, bq);
      pf[0].u4[0] = bq; pf[0].u4[2] = a;
      unsigned c = W11, d = W01; plswap(c, d);
      pf[0].u4[1] = d; pf[0].u4[3] = c;
      unsigned e = W30, f = W20; plswap(e, f);
      pf[1].u4[0] = f; pf[1].u4[2] = e;
      unsigned g = W31, hh = W21; plswap(g, hh);
      pf[1].u4[1] = hh; pf[1].u4[3] = g;
    }
    // ---- k-half 1 ----
    {
      f32x16 s;
#pragma unroll
      for (int i = 0; i < 16; ++i) s[i] = 0.f;
      const int kr = 32 + l31;
      __builtin_amdgcn_s_setprio(1);
#pragma unroll
      for (int ds = 0; ds < 4; ++ds) {
        short8 kf = *(const short8*)(kb + (kr << 7) +
                                     (((ds << 5) + (l5 << 4)) ^ ((kr & 7) << 4)));
        s = __builtin_amdgcn_mfma_f32_32x32x16_bf16(kf, qf[ds], s, 0, 0, 0);
      }
      __builtin_amdgcn_s_setprio(0);
      float p[16];
#pragma unroll
      for (int i = 0; i < 16; ++i) {
        p[i] = exp2f(s[i] * SCALE2);
        lacc += p[i];
      }
      unsigned W00 = cvtpk(p[0], p[1]), W01 = cvtpk(p[2], p[3]);
      unsigned W10 = cvtpk(p[4], p[5]), W11 = cvtpk(p[6], p[7]);
      unsigned W20 = cvtpk(p[8], p[9]), W21 = cvtpk(p[10], p[11]);
      unsigned W30 = cvtpk(p[12], p[13]), W31 = cvtpk(p[14], p[15]);
      unsigned a = W10, bq = W00; plswap(a, bq);
      pf[2].u4[0] = bq; pf[2].u4[2] = a;
      unsigned c = W11, d = W01; plswap(c, d);
      pf[2].u4[1] = d; pf[2].u4[3] = c;
      unsigned e = W30, f = W20; plswap(e, f);
      pf[3].u4[0] = f; pf[3].u4[2] = e;
      unsigned g = W31, hh = W21; plswap(g, hh);
      pf[3].u4[1] = hh; pf[3].u4[3] = g;
    }

    // ---- O += V^T x P over ALL 128 e ----
    __builtin_amdgcn_s_setprio(1);
#pragma unroll
    for (int eb = 0; eb < 4; ++eb) {
      const int vrow = (eb << 5) + l31;
#pragma unroll
      for (int ks = 0; ks < 4; ++ks) {
        short8 vf = *(const short8*)(vb + (vrow << 7) +
                                     (((ks << 5) + (l5 << 4)) ^ ((vrow & 7) << 4)));
        o[eb] = __builtin_amdgcn_mfma_f32_32x32x16_bf16(vf, pf[ks].s8, o[eb], 0, 0, 0);
      }
    }
    __builtin_amdgcn_s_setprio(0);
    const int tmp = c0b; c0b = c1b; c1b = c2b; c2b = tmp;
  }
#undef ATTN_STAGE

  // ---- finalize: full row sum = this l5-half + partner half ----
  lacc += __shfl_xor(lacc, 32, 64);
  const float rl = 1.f / lacc;
  const int t = q0 + (w << 5) + l31;

  // ---- epilogue: uoT[b][t][h*128+e] = bf16(u * o / l) ----
#pragma unroll
  for (int eb = 0; eb < 4; ++eb) {
#pragma unroll
    for (int g = 0; g < 4; ++g) {
      const int e4 = (eb << 5) + (g << 3) + (l5 << 2);
      const int eg = (h << 7) + e4;
      ushort4 outv;
      unsigned short* op = (unsigned short*)&outv;
#pragma unroll
      for (int j = 0; j < 4; ++j) {
        const int i = (g << 2) + j;
        const float oo = o[eb][i] * rl;
        const float uu = b2f(u[((((size_t)b << 10) + eg + j) << 10) + t]);
        op[j] = f2b(oo * uu);
      }
      *(ushort4*)(uoT + ((((size_t)b << 10) + t) << 10) + eg) = outv;
    }
  }
}

// ---------------- GEMM C: out^T = uoT(1024x1024) @ W_out^T, +bias+residual -> y(bf16) ----------------
__global__ __launch_bounds__(256) void gemm_c_kernel(const unsigned short* __restrict__ uoT,
                                                     const unsigned short* __restrict__ WoutB,
                                                     const float* __restrict__ x,
                                                     const float* __restrict__ b_out,
                                                     unsigned short* __restrict__ y) {
  __shared__ __align__(16) unsigned short lsA[12288];
  __shared__ __align__(16) unsigned short lsB[12288];
  // XCD swizzle: 256 = 8 x 32
  const int bid = ((blockIdx.x & 7) * 32) + (blockIdx.x >> 3);
  const int b = bid >> 5;
  const int rem = bid & 31;
  const int m0 = (rem >> 2) << 7;  // t tile
  const int n0 = (rem & 3) << 7;   // c tile
  f32x4 acc[4][4];
  const f32x4 z4 = {0.f, 0.f, 0.f, 0.f};
#pragma unroll
  for (int mi = 0; mi < 4; ++mi)
#pragma unroll
    for (int ni = 0; ni < 4; ++ni) acc[mi][ni] = z4;

  const unsigned short* Ag = uoT + ((size_t)b << 20) + ((size_t)m0 << 10);
  const unsigned short* Bg = WoutB + ((size_t)n0 << 10);
  gemm_bt_core(Ag, Bg, 1024, 1024, 1024, lsA, lsB, acc);

  const int lane = threadIdx.x & 63;
  const int w = threadIdx.x >> 6;
  const int wr = w >> 1, wc = w & 1;
#pragma unroll
  for (int mi = 0; mi < 4; ++mi) {
    const int t4 = m0 + (wr << 6) + (mi << 4) + ((lane >> 4) << 2);
#pragma unroll
    for (int ni = 0; ni < 4; ++ni) {
      const int c = n0 + (wc << 6) + (ni << 4) + (lane & 15);
      const size_t base = ((((size_t)b << 9) + c) << 10) + t4;
      const f32x4 xv = *(const f32x4*)(x + base);
      const float bo = b_out[c];
      ushort4 ov;
      unsigned short* op = (unsigned short*)&ov;
#pragma unroll
      for (int i = 0; i < 4; ++i) op[i] = f2b(acc[mi][ni][i] + bo + xv[i]);
      *(ushort4*)(y + base) = ov;
    }
  }
}

// ---------------- RMSNorm over C per (b,t): y bf16 in, f32 out ----------------
__global__ __launch_bounds__(256) void rms_kernel(const unsigned short* __restrict__ y,
                                                  const float* __restrict__ gamma,
                                                  float* __restrict__ out) {
  __shared__ float part[8][32];
  __shared__ float rmsv[32];
  const int bid = blockIdx.x;
  const int b = bid >> 5;
  const int t0 = (bid & 31) << 5;  // 32 t per block
  const int tid = threadIdx.x;
  const int tt = tid & 31, cg = tid >> 5;  // cg 0..7, 64 c each
  const int t = t0 + tt;
  float vals[64];
  float ss = 0.f;
#pragma unroll
  for (int ci = 0; ci < 64; ++ci) {
    const int c = (cg << 6) + ci;
    const float vv = b2f(y[((((size_t)b << 9) + c) << 10) + t]);
    vals[ci] = vv;
    ss += vv * vv;
  }
  part[cg][tt] = ss;
  __syncthreads();
  if (tid < 32) {
    float tot = 0.f;
#pragma unroll
    for (int g = 0; g < 8; ++g) tot += part[g][tid];
    rmsv[tid] = rsqrtf(tot / 512.f + 1e-5f);
  }
  __syncthreads();
  const float rm = rmsv[tt];
#pragma unroll
  for (int ci = 0; ci < 64; ++ci) {
    const int c = (cg << 6) + ci;
    out[((((size_t)b << 9) + c) << 10) + t] = vals[ci] * rm * gamma[c];
  }
}

extern "C" void kernel_launch(void* const* d_in, const int* in_sizes, int n_in, void* d_out,
                              int out_size, void* d_ws, size_t ws_size, hipStream_t stream) {
  const float* x = (const float*)d_in[0];
  const float* W_in = (const float*)d_in[1];
  const float* b_in = (const float*)d_in[2];
  const float* W_attn = (const float*)d_in[3];
  const float* b_attn = (const float*)d_in[4];
  const float* w_q = (const float*)d_in[5];
  const float* b_q = (const float*)d_in[6];
  const float* w_k = (const float*)d_in[7];
  const float* b_k = (const float*)d_in[8];
  const float* W_out = (const float*)d_in[9];
  const float* b_out = (const float*)d_in[10];
  const float* gamma = (const float*)d_in[11];
  float* out = (float*)d_out;

  char* ws = (char*)d_ws;
  size_t off = 0;
  auto alloc = [&](size_t bytes) {
    char* p = ws + off;
    off += (bytes + 255) & ~(size_t)255;
    return p;
  };
  unsigned short* Wcat = (unsigned short*)alloc((size_t)2560 * 512 * 2);
  unsigned short* WoutB = (unsigned short*)alloc((size_t)512 * 1024 * 2);
  unsigned short* xT = (unsigned short*)alloc((size_t)8 * 1024 * 512 * 2);
  unsigned short* u = (unsigned short*)alloc((size_t)8 * 1024 * 1024 * 2);
  unsigned short* v = (unsigned short*)alloc((size_t)8 * 1024 * 1024 * 2);
  unsigned short* qT = (unsigned short*)alloc((size_t)8 * 8 * 1024 * 64 * 2);
  unsigned short* kT = (unsigned short*)alloc((size_t)8 * 8 * 1024 * 64 * 2);
  unsigned short* uoT = (unsigned short*)alloc((size_t)8 * 1024 * 1024 * 2);
  unsigned short* y = (unsigned short*)alloc((size_t)8 * 512 * 1024 * 2);
  if (off > ws_size) return;  // fail visibly (poisoned output)

  prep_w_kernel<<<896, 256, 0, stream>>>(W_in, W_attn, W_out, Wcat, WoutB);
  transpose_x_kernel<<<4096, 256, 0, stream>>>(x, xT);
  gemm_a_kernel<<<1280, 256, 0, stream>>>(Wcat, xT, b_in, b_attn, w_q, b_q, w_k, b_k, u, v, qT,
                                          kT);
  attn_kernel<<<512, 256, 0, stream>>>(qT, kT, v, u, uoT);
  gemm_c_kernel<<<256, 256, 0, stream>>>(uoT, WoutB, x, b_out, y);
  rms_kernel<<<256, 256, 0, stream>>>(y, gamma, out);
}

// Round 14
// 120.701 us; speedup vs baseline: 1.0974x; 1.0273x over previous
//
#include <hip/hip_runtime.h>

typedef __attribute__((ext_vector_type(8))) short short8;
typedef __attribute__((ext_vector_type(4))) float f32x4;
typedef __attribute__((ext_vector_type(16))) float f32x16;

__device__ __forceinline__ unsigned short f2b(float f) {
  union { float f; unsigned u; } x; x.f = f;
  unsigned r = (x.u + 0x7fffu + ((x.u >> 16) & 1u)) >> 16;
  return (unsigned short)r;
}
__device__ __forceinline__ float b2f(unsigned short b) {
  union { unsigned u; float f; } x; x.u = ((unsigned)b) << 16;
  return x.f;
}
__device__ __forceinline__ unsigned cvtpk(float lo, float hi) {
  unsigned r;
  asm("v_cvt_pk_bf16_f32 %0, %1, %2" : "=v"(r) : "v"(lo), "v"(hi));
  return r;
}
__device__ __forceinline__ void plswap(unsigned& a, unsigned& b) {
  asm volatile("v_permlane32_swap_b32 %0, %1" : "+v"(a), "+v"(b));
}

#define GLDS16(gp, lp)                                                                  \
  __builtin_amdgcn_global_load_lds((const __attribute__((address_space(1))) void*)(gp), \
                                   (__attribute__((address_space(3))) void*)(lp), 16, 0, 0)

// ---------------- fused prep: weight conversion + x transpose ----------------
__global__ __launch_bounds__(256) void prep_kernel(const float* __restrict__ x,
                                                   const float* __restrict__ W_in,
                                                   const float* __restrict__ W_attn,
                                                   const float* __restrict__ W_out,
                                                   unsigned short* __restrict__ Wcat,
                                                   unsigned short* __restrict__ WoutB,
                                                   unsigned short* __restrict__ xT) {
  if (blockIdx.x < 4096) {
    // transpose: xT[b][t][c] = bf16(x[b][c][t]); b = bid&7 aligns batch to XCD
    __shared__ float tile[32][33];
    const int bid = blockIdx.x;
    const int b = bid & 7;
    const int rem = bid >> 3;
    const int c0 = (rem >> 5) << 5;
    const int t0 = (rem & 31) << 5;
    const int tj = threadIdx.x & 31, ti = threadIdx.x >> 5;  // ti 0..7
#pragma unroll
    for (int r = 0; r < 32; r += 8)
      tile[ti + r][tj] = x[(((size_t)b << 9) + c0 + ti + r) * 1024 + t0 + tj];
    __syncthreads();
#pragma unroll
    for (int r = 0; r < 32; r += 8)
      xT[(((size_t)b << 10) + t0 + ti + r) * 512 + c0 + tj] = f2b(tile[tj][ti + r]);
  } else {
    const int n1 = 2048 * 512, n2 = 512 * 512, n3 = 512 * 1024;
    for (int i = (blockIdx.x - 4096) * 256 + threadIdx.x; i < n1 + n2 + n3; i += 896 * 256) {
      if (i < n1) Wcat[i] = f2b(W_in[i]);
      else if (i < n1 + n2) Wcat[i] = f2b(W_attn[i - n1]);
      else WoutB[i - n1 - n2] = f2b(W_out[i - n1 - n2]);
    }
  }
}

// ---------------- shared GEMM core: 128x128 tile, BK=32, 4 waves, 3-buf, 1 barrier/step ----------------
__device__ __forceinline__ void gemm_stage(const unsigned short* Ag, const unsigned short* Bg,
                                           int lda, int ldb, int k0, unsigned short* lsA,
                                           unsigned short* lsB, int buf, int sr, int sk,
                                           int ldst) {
  const int bb = buf * 8192;  // bytes per buffer
  GLDS16(Ag + (size_t)sr * lda + k0 + sk, (char*)lsA + bb + ldst);
  GLDS16(Ag + (size_t)(sr + 64) * lda + k0 + sk, (char*)lsA + bb + 4096 + ldst);
  GLDS16(Bg + (size_t)sr * ldb + k0 + sk, (char*)lsB + bb + ldst);
  GLDS16(Bg + (size_t)(sr + 64) * ldb + k0 + sk, (char*)lsB + bb + 4096 + ldst);
}

__device__ __forceinline__ void gemm_bt_core(const unsigned short* __restrict__ Ag,
                                             const unsigned short* __restrict__ Bg, int lda,
                                             int ldb, int K, unsigned short* lsA,
                                             unsigned short* lsB, f32x4 acc[4][4]) {
  const int tid = threadIdx.x;
  const int lane = tid & 63;
  const int w = tid >> 6;
  const int wr = w >> 1, wc = w & 1;
  const int sr = tid >> 2;  // staging row 0..63 (row sr and sr+64 share (sr>>1)&3 mod 4)
  const int sk = (((tid & 3) ^ ((sr >> 1) & 3)) << 3);  // swizzled global k-slot (elems)
  const int ldst = (tid >> 6) << 10;  // wave-uniform LDS byte base

  const int nt = K >> 5;
  int c0b = 0, c1b = 1, c2b = 2;
  gemm_stage(Ag, Bg, lda, ldb, 0, lsA, lsB, 0, sr, sk, ldst);
  gemm_stage(Ag, Bg, lda, ldb, 32, lsA, lsB, 1, sr, sk, ldst);
  for (int t = 0; t < nt; ++t) {
    if (t + 1 < nt) {
      asm volatile("s_waitcnt vmcnt(4)" ::: "memory");  // tile t landed (leaves t+1 in flight)
    } else {
      asm volatile("s_waitcnt vmcnt(0)" ::: "memory");
    }
    __builtin_amdgcn_s_barrier();  // all threads' tile-t loads visible; t-1 reads done
    if (t + 2 < nt)
      gemm_stage(Ag, Bg, lda, ldb, (t + 2) << 5, lsA, lsB, c2b, sr, sk, ldst);
    short8 af[4], bfr[4];
    const int bb = c0b * 8192;
    const int ko = (lane >> 4) << 4;  // byte slot within 64B row
    const int ra = (wr << 6) + (lane & 15);
    const int rb = (wc << 6) + (lane & 15);
#pragma unroll
    for (int mi = 0; mi < 4; ++mi) {
      const int rowA = ra + (mi << 4);
      af[mi] = *(const short8*)((const char*)lsA + bb + (rowA << 6) +
                                (ko ^ (((rowA >> 1) & 3) << 4)));
    }
#pragma unroll
    for (int ni = 0; ni < 4; ++ni) {
      const int rowB = rb + (ni << 4);
      bfr[ni] = *(const short8*)((const char*)lsB + bb + (rowB << 6) +
                                 (ko ^ (((rowB >> 1) & 3) << 4)));
    }
#pragma unroll
    for (int mi = 0; mi < 4; ++mi)
#pragma unroll
      for (int ni = 0; ni < 4; ++ni)
        acc[mi][ni] =
            __builtin_amdgcn_mfma_f32_16x16x32_bf16(af[mi], bfr[ni], acc[mi][ni], 0, 0, 0);
    const int tmp = c0b; c0b = c1b; c1b = c2b; c2b = tmp;
  }
}

// ---------------- GEMM A: [W_in;W_attn](2560x512) @ x[b](512x1024) ----------------
__global__ __launch_bounds__(256) void gemm_a_kernel(
    const unsigned short* __restrict__ Wcat, const unsigned short* __restrict__ xT,
    const float* __restrict__ b_in, const float* __restrict__ b_attn,
    const float* __restrict__ w_q, const float* __restrict__ b_q, const float* __restrict__ w_k,
    const float* __restrict__ b_k, unsigned short* __restrict__ u, unsigned short* __restrict__ v,
    unsigned short* __restrict__ qT, unsigned short* __restrict__ kT) {
  __shared__ __align__(16) unsigned short lsA[12288];  // 3 x 8KB
  __shared__ __align__(16) unsigned short lsB[12288];
  const int bid = ((blockIdx.x & 7) * 160) + (blockIdx.x >> 3);
  const int b = bid / 160;
  const int rem = bid % 160;
  const int m0 = (rem >> 3) << 7;
  const int n0 = (rem & 7) << 7;
  f32x4 acc[4][4];
  const f32x4 z4 = {0.f, 0.f, 0.f, 0.f};
#pragma unroll
  for (int mi = 0; mi < 4; ++mi)
#pragma unroll
    for (int ni = 0; ni < 4; ++ni) acc[mi][ni] = z4;

  const unsigned short* Ag = Wcat + (size_t)m0 * 512;
  const unsigned short* Bg = xT + ((size_t)b << 19) + ((size_t)n0 << 9);
  gemm_bt_core(Ag, Bg, 512, 512, 512, lsA, lsB, acc);

  const int lane = threadIdx.x & 63;
  const int w = threadIdx.x >> 6;
  const int wr = w >> 1, wc = w & 1;
#pragma unroll
  for (int mi = 0; mi < 4; ++mi) {
    const int row0 = m0 + (wr << 6) + (mi << 4) + ((lane >> 4) << 2);
#pragma unroll
    for (int ni = 0; ni < 4; ++ni) {
      const int col = n0 + (wc << 6) + (ni << 4) + (lane & 15);
      if (row0 < 2048) {
#pragma unroll
        for (int i = 0; i < 4; ++i) {
          const int row = row0 + i;
          const float s = acc[mi][ni][i] + b_in[row];
          const float r = s / (1.f + __expf(-s));  // silu
          if (row < 1024)
            u[((((size_t)b << 10) + row) << 10) + col] = f2b(r);
          else
            v[((((size_t)b << 10) + (row - 1024)) << 10) + col] = f2b(r);
        }
      } else {
        const int c0 = row0 - 2048;
        ushort4 qv, kv;
        unsigned short* qp = (unsigned short*)&qv;
        unsigned short* kp = (unsigned short*)&kv;
#pragma unroll
        for (int i = 0; i < 4; ++i) {
          const int c = c0 + i;
          const float z = acc[mi][ni][i] + b_attn[c];
          qp[i] = f2b(z * w_q[c] + b_q[c]);
          kp[i] = f2b(z * w_k[c] + b_k[c]);
        }
        const int h = c0 >> 6, d = c0 & 63;
        const size_t base = ((((size_t)b * 8 + h) << 10) + col) * 64 + d;
        *(ushort4*)(qT + base) = qv;
        *(ushort4*)(kT + base) = kv;
      }
    }
  }
}

// ---------------- flash attention v6: T15 double-pipeline (PV consumes prev tile's P) ----------------
// iter kt: vmcnt(6); barrier; [QK(kt) || PV(kt-1) interleaved 24-MFMA cluster];
// pack(kt)->pfP; barrier; stage(kt+2) into buf[(kt+2)%3] (= tile kt-1's buffer,
// whose K was read at iter kt-1 and V by PV this iter -- both sealed by barrier2).
__global__ __launch_bounds__(256, 2) void attn_kernel(const unsigned short* __restrict__ qT,
                                                      const unsigned short* __restrict__ kT,
                                                      const unsigned short* __restrict__ v,
                                                      const unsigned short* __restrict__ u,
                                                      unsigned short* __restrict__ uoT) {
  __shared__ __align__(16) unsigned short Kls[3 * 4096];  // 3 x [64 k][64 d] swizzled
  __shared__ __align__(16) unsigned short Vls[3 * 8192];  // 3 x [128 e][64 t] swizzled
  const float SCALE2 = 0.20037430567f;  // (log(1024)/log(512)/sqrt(64)) * log2(e)
  const int bx = blockIdx.x;
  const int xcd = bx & 7, idx = bx >> 3;  // idx 0..63
  const int bh = (xcd << 3) + (idx & 7);
  const int qb = idx >> 3;  // 0..7
  const int b = bh >> 3, h = bh & 7;
  const int tid = threadIdx.x;
  const int lane = tid & 63;
  const int w = tid >> 6;  // qw 0..3
  const int l5 = lane >> 5;
  const int l31 = lane & 31;
  const int q0 = qb << 7;

  const unsigned short* qh = qT + ((size_t)bh << 16);
  const unsigned short* kh = kT + ((size_t)bh << 16);
  const unsigned short* vh = v + ((((size_t)b << 10) + (h << 7)) << 10);

  short8 qf[4];
#pragma unroll
  for (int ds = 0; ds < 4; ++ds)
    qf[ds] = *(const short8*)(qh + (size_t)(q0 + (w << 5) + l31) * 64 + (ds << 4) + (l5 << 3));

  f32x16 o[4];
#pragma unroll
  for (int eb = 0; eb < 4; ++eb)
#pragma unroll
    for (int i = 0; i < 16; ++i) o[eb][i] = 0.f;
  float lacc = 0.f;

  const int srow = tid >> 3;                         // 0..31
  const int scol = (((tid & 7) ^ (srow & 7)) << 3);  // pre-swizzled src col (elems)

#define ATTN_STAGE(buf, kt)                                                            \
  {                                                                                    \
    const int t2 = (kt) << 6;                                                          \
    char* kbase = (char*)Kls + (buf)*8192;                                             \
    char* vbase = (char*)Vls + (buf)*16384;                                            \
    GLDS16(kh + (size_t)(t2 + srow) * 64 + scol, kbase + (w << 10));                   \
    GLDS16(kh + (size_t)(t2 + 32 + srow) * 64 + scol, kbase + 4096 + (w << 10));       \
    GLDS16(vh + ((size_t)srow << 10) + t2 + scol, vbase + (w << 10));                  \
    GLDS16(vh + ((size_t)(32 + srow) << 10) + t2 + scol, vbase + 4096 + (w << 10));    \
    GLDS16(vh + ((size_t)(64 + srow) << 10) + t2 + scol, vbase + 8192 + (w << 10));    \
    GLDS16(vh + ((size_t)(96 + srow) << 10) + t2 + scol, vbase + 12288 + (w << 10));   \
  }

#define KREAD(kbp, kr, ds)                                                             \
  (*(const short8*)((kbp) + ((kr) << 7) + ((((ds) << 5) + (l5 << 4)) ^ (((kr)&7) << 4))))
#define VREAD(vbp, vrow, ks)                                                           \
  (*(const short8*)((vbp) + ((vrow) << 7) + ((((ks) << 5) + (l5 << 4)) ^ (((vrow)&7) << 4))))

#define PACK(sv, out0, out1)                                                           \
  do {                                                                                 \
    float p_[16];                                                                      \
    _Pragma("unroll") for (int i_ = 0; i_ < 16; ++i_) {                                \
      p_[i_] = exp2f(sv[i_] * SCALE2);                                                 \
      lacc += p_[i_];                                                                  \
    }                                                                                  \
    unsigned W00 = cvtpk(p_[0], p_[1]), W01 = cvtpk(p_[2], p_[3]);                     \
    unsigned W10 = cvtpk(p_[4], p_[5]), W11 = cvtpk(p_[6], p_[7]);                     \
    unsigned W20 = cvtpk(p_[8], p_[9]), W21 = cvtpk(p_[10], p_[11]);                   \
    unsigned W30 = cvtpk(p_[12], p_[13]), W31 = cvtpk(p_[14], p_[15]);                 \
    unsigned a_ = W10, b_ = W00;                                                       \
    plswap(a_, b_);                                                                    \
    (out0).u4[0] = b_; (out0).u4[2] = a_;                                              \
    unsigned c_ = W11, d_ = W01;                                                       \
    plswap(c_, d_);                                                                    \
    (out0).u4[1] = d_; (out0).u4[3] = c_;                                              \
    unsigned e_ = W30, f_ = W20;                                                       \
    plswap(e_, f_);                                                                    \
    (out1).u4[0] = f_; (out1).u4[2] = e_;                                              \
    unsigned g_ = W31, h_ = W21;                                                       \
    plswap(g_, h_);                                                                    \
    (out1).u4[1] = h_; (out1).u4[3] = g_;                                              \
  } while (0)

  union U8 { short8 s8; unsigned u4[4]; };
  U8 pfP[4];

  ATTN_STAGE(0, 0);
  ATTN_STAGE(1, 1);

  // ---- iter 0: QK(0) + pack only ----
  asm volatile("s_waitcnt vmcnt(6)" ::: "memory");
  __builtin_amdgcn_s_barrier();
  {
    const char* kb = (const char*)Kls;
    f32x16 s0, s1;
#pragma unroll
    for (int i = 0; i < 16; ++i) { s0[i] = 0.f; s1[i] = 0.f; }
    __builtin_amdgcn_s_setprio(1);
#pragma unroll
    for (int ds = 0; ds < 4; ++ds) {
      short8 kfA = KREAD(kb, l31, ds);
      s0 = __builtin_amdgcn_mfma_f32_32x32x16_bf16(kfA, qf[ds], s0, 0, 0, 0);
      short8 kfB = KREAD(kb, 32 + l31, ds);
      s1 = __builtin_amdgcn_mfma_f32_32x32x16_bf16(kfB, qf[ds], s1, 0, 0, 0);
    }
    __builtin_amdgcn_s_setprio(0);
    PACK(s0, pfP[0], pfP[1]);
    PACK(s1, pfP[2], pfP[3]);
  }
  __builtin_amdgcn_s_barrier();
  ATTN_STAGE(2, 2);

  int ck = 1, cv = 0;  // ck = kt%3, cv = (kt-1)%3
  for (int kt = 1; kt < 16; ++kt) {
    if (kt < 15) {
      asm volatile("s_waitcnt vmcnt(6)" ::: "memory");  // tile kt landed
    } else {
      asm volatile("s_waitcnt vmcnt(0)" ::: "memory");
    }
    __builtin_amdgcn_s_barrier();  // K/V[kt] visible to all waves

    const char* kb = (const char*)Kls + ck * 8192;
    const char* vb = (const char*)Vls + cv * 16384;

    // preload K fragments
    short8 kfA[4], kfB[4];
#pragma unroll
    for (int ds = 0; ds < 4; ++ds) {
      kfA[ds] = KREAD(kb, l31, ds);
      kfB[ds] = KREAD(kb, 32 + l31, ds);
    }

    // ---- interleaved: QK(kt) (8 MFMA) || PV(kt-1) (16 MFMA) ----
    f32x16 s0, s1;
#pragma unroll
    for (int i = 0; i < 16; ++i) { s0[i] = 0.f; s1[i] = 0.f; }
    __builtin_amdgcn_s_setprio(1);
#pragma unroll
    for (int ks = 0; ks < 4; ++ks) {
      s0 = __builtin_amdgcn_mfma_f32_32x32x16_bf16(kfA[ks], qf[ks], s0, 0, 0, 0);
      s1 = __builtin_amdgcn_mfma_f32_32x32x16_bf16(kfB[ks], qf[ks], s1, 0, 0, 0);
#pragma unroll
      for (int eb = 0; eb < 4; ++eb) {
        short8 vf = VREAD(vb, (eb << 5) + l31, ks);
        o[eb] = __builtin_amdgcn_mfma_f32_32x32x16_bf16(vf, pfP[ks].s8, o[eb], 0, 0, 0);
      }
    }
    __builtin_amdgcn_s_setprio(0);

    // ---- pack(kt) -> pfP (feeds next iter's PV) ----
    U8 pfN[4];
    PACK(s0, pfN[0], pfN[1]);
    PACK(s1, pfN[2], pfN[3]);
#pragma unroll
    for (int i = 0; i < 4; ++i) pfP[i] = pfN[i];

    if (kt + 2 < 16) {
      __builtin_amdgcn_s_barrier();  // all waves done reading V[kt-1] / K[kt-1]
      ATTN_STAGE(cv, kt + 2);        // (kt+2)%3 == cv
    }
    const int third = 3 - ck - cv;
    cv = ck;
    ck = third;
  }

  // ---- tail: PV(15) ----
  {
    const char* vb = (const char*)Vls + cv * 16384;
    __builtin_amdgcn_s_setprio(1);
#pragma unroll
    for (int ks = 0; ks < 4; ++ks) {
#pragma unroll
      for (int eb = 0; eb < 4; ++eb) {
        short8 vf = VREAD(vb, (eb << 5) + l31, ks);
        o[eb] = __builtin_amdgcn_mfma_f32_32x32x16_bf16(vf, pfP[ks].s8, o[eb], 0, 0, 0);
      }
    }
    __builtin_amdgcn_s_setprio(0);
  }
#undef ATTN_STAGE
#undef KREAD
#undef VREAD
#undef PACK

  // ---- finalize: full row sum = this l5-half + partner half ----
  lacc += __shfl_xor(lacc, 32, 64);
  const float rl = 1.f / lacc;
  const int t = q0 + (w << 5) + l31;

  // ---- epilogue: uoT[b][t][h*128+e] = bf16(u * o / l) ----
#pragma unroll
  for (int eb = 0; eb < 4; ++eb) {
#pragma unroll
    for (int g = 0; g < 4; ++g) {
      const int e4 = (eb << 5) + (g << 3) + (l5 << 2);
      const int eg = (h << 7) + e4;
      ushort4 outv;
      unsigned short* op = (unsigned short*)&outv;
#pragma unroll
      for (int j = 0; j < 4; ++j) {
        const int i = (g << 2) + j;
        const float oo = o[eb][i] * rl;
        const float uu = b2f(u[((((size_t)b << 10) + eg + j) << 10) + t]);
        op[j] = f2b(oo * uu);
      }
      *(ushort4*)(uoT + ((((size_t)b << 10) + t) << 10) + eg) = outv;
    }
  }
}

// ---------------- GEMM C: out^T = uoT(1024x1024) @ W_out^T, +bias+residual -> y(bf16) ----------------
__global__ __launch_bounds__(256) void gemm_c_kernel(const unsigned short* __restrict__ uoT,
                                                     const unsigned short* __restrict__ WoutB,
                                                     const float* __restrict__ x,
                                                     const float* __restrict__ b_out,
                                                     unsigned short* __restrict__ y) {
  __shared__ __align__(16) unsigned short lsA[12288];
  __shared__ __align__(16) unsigned short lsB[12288];
  const int bid = ((blockIdx.x & 7) * 32) + (blockIdx.x >> 3);
  const int b = bid >> 5;
  const int rem = bid & 31;
  const int m0 = (rem >> 2) << 7;  // t tile
  const int n0 = (rem & 3) << 7;   // c tile
  f32x4 acc[4][4];
  const f32x4 z4 = {0.f, 0.f, 0.f, 0.f};
#pragma unroll
  for (int mi = 0; mi < 4; ++mi)
#pragma unroll
    for (int ni = 0; ni < 4; ++ni) acc[mi][ni] = z4;

  const unsigned short* Ag = uoT + ((size_t)b << 20) + ((size_t)m0 << 10);
  const unsigned short* Bg = WoutB + ((size_t)n0 << 10);
  gemm_bt_core(Ag, Bg, 1024, 1024, 1024, lsA, lsB, acc);

  const int lane = threadIdx.x & 63;
  const int w = threadIdx.x >> 6;
  const int wr = w >> 1, wc = w & 1;
#pragma unroll
  for (int mi = 0; mi < 4; ++mi) {
    const int t4 = m0 + (wr << 6) + (mi << 4) + ((lane >> 4) << 2);
#pragma unroll
    for (int ni = 0; ni < 4; ++ni) {
      const int c = n0 + (wc << 6) + (ni << 4) + (lane & 15);
      const size_t base = ((((size_t)b << 9) + c) << 10) + t4;
      const f32x4 xv = *(const f32x4*)(x + base);
      const float bo = b_out[c];
      ushort4 ov;
      unsigned short* op = (unsigned short*)&ov;
#pragma unroll
      for (int i = 0; i < 4; ++i) op[i] = f2b(acc[mi][ni][i] + bo + xv[i]);
      *(ushort4*)(y + base) = ov;
    }
  }
}

// ---------------- RMSNorm over C per (b,t): y bf16 in, f32 out ----------------
__global__ __launch_bounds__(256) void rms_kernel(const unsigned short* __restrict__ y,
                                                  const float* __restrict__ gamma,
                                                  float* __restrict__ out) {
  __shared__ float part[8][32];
  __shared__ float rmsv[32];
  const int bid = blockIdx.x;
  const int b = bid >> 5;
  const int t0 = (bid & 31) << 5;  // 32 t per block
  const int tid = threadIdx.x;
  const int tt = tid & 31, cg = tid >> 5;  // cg 0..7, 64 c each
  const int t = t0 + tt;
  float vals[64];
  float ss = 0.f;
#pragma unroll
  for (int ci = 0; ci < 64; ++ci) {
    const int c = (cg << 6) + ci;
    const float vv = b2f(y[((((size_t)b << 9) + c) << 10) + t]);
    vals[ci] = vv;
    ss += vv * vv;
  }
  part[cg][tt] = ss;
  __syncthreads();
  if (tid < 32) {
    float tot = 0.f;
#pragma unroll
    for (int g = 0; g < 8; ++g) tot += part[g][tid];
    rmsv[tid] = rsqrtf(tot / 512.f + 1e-5f);
  }
  __syncthreads();
  const float rm = rmsv[tt];
#pragma unroll
  for (int ci = 0; ci < 64; ++ci) {
    const int c = (cg << 6) + ci;
    out[((((size_t)b << 9) + c) << 10) + t] = vals[ci] * rm * gamma[c];
  }
}

extern "C" void kernel_launch(void* const* d_in, const int* in_sizes, int n_in, void* d_out,
                              int out_size, void* d_ws, size_t ws_size, hipStream_t stream) {
  const float* x = (const float*)d_in[0];
  const float* W_in = (const float*)d_in[1];
  const float* b_in = (const float*)d_in[2];
  const float* W_attn = (const float*)d_in[3];
  const float* b_attn = (const float*)d_in[4];
  const float* w_q = (const float*)d_in[5];
  const float* b_q = (const float*)d_in[6];
  const float* w_k = (const float*)d_in[7];
  const float* b_k = (const float*)d_in[8];
  const float* W_out = (const float*)d_in[9];
  const float* b_out = (const float*)d_in[10];
  const float* gamma = (const float*)d_in[11];
  float* out = (float*)d_out;

  char* ws = (char*)d_ws;
  size_t off = 0;
  auto alloc = [&](size_t bytes) {
    char* p = ws + off;
    off += (bytes + 255) & ~(size_t)255;
    return p;
  };
  unsigned short* Wcat = (unsigned short*)alloc((size_t)2560 * 512 * 2);
  unsigned short* WoutB = (unsigned short*)alloc((size_t)512 * 1024 * 2);
  unsigned short* xT = (unsigned short*)alloc((size_t)8 * 1024 * 512 * 2);
  unsigned short* u = (unsigned short*)alloc((size_t)8 * 1024 * 1024 * 2);
  unsigned short* v = (unsigned short*)alloc((size_t)8 * 1024 * 1024 * 2);
  unsigned short* qT = (unsigned short*)alloc((size_t)8 * 8 * 1024 * 64 * 2);
  unsigned short* kT = (unsigned short*)alloc((size_t)8 * 8 * 1024 * 64 * 2);
  unsigned short* uoT = (unsigned short*)alloc((size_t)8 * 1024 * 1024 * 2);
  unsigned short* y = (unsigned short*)alloc((size_t)8 * 512 * 1024 * 2);
  if (off > ws_size) return;  // fail visibly (poisoned output)

  prep_kernel<<<4992, 256, 0, stream>>>(x, W_in, W_attn, W_out, Wcat, WoutB, xT);
  gemm_a_kernel<<<1280, 256, 0, stream>>>(Wcat, xT, b_in, b_attn, w_q, b_q, w_k, b_k, u, v, qT,
                                          kT);
  attn_kernel<<<512, 256, 0, stream>>>(qT, kT, v, u, uoT);
  gemm_c_kernel<<<256, 256, 0, stream>>>(uoT, WoutB, x, b_out, y);
  rms_kernel<<<256, 256, 0, stream>>>(y, gamma, out);
}